// Round 9
// baseline (1188.776 us; speedup 1.0000x reference)
//
#include <hip/hip_runtime.h>
#include <stdint.h>

#define N_NODES   50000
#define N_GENES   512
#define N_EDGES   800000
#define N_ITERS   5

#define C_CHUNKS  250
#define CHUNK_E   3200          // 250 * 3200 = 800000; 3200/64 = 50 subchunks exactly
#define NSUB      (CHUNK_E / 64)

// ---- packed-sparse x representation (one 1536-B record per row) ----
// rec dwords [0..255]   : packed nonzero VALUES (f32), padded with 0.0f to a
//                         multiple of 64 entries (1..4 "rounds").
// rec dwords [256..383] : gene LDS BYTE-OFFSETS (u16, gene<<2; padding entries
//                         point at the per-wave scratch area 2048 + 4*(pos&63),
//                         distinct per lane within a round).
// rounds (1..4) per row in a u8 array (rnd_a / rnd_b).
#define REC_DW     384
#define REC_BYTES  1536

// ws layout sizes (bytes)
#define RECS_BYTES (50000ull * REC_BYTES + 256ull)
#define IMP_BYTES  3200000ull
#define CNT_BYTES  200000ull
#define PTR_BYTES  200004ull
#define CCOL_BYTES 3200000ull
#define CW_BYTES   3200000ull
#define RND_BYTES  50048ull
#define BSUM_BYTES 1024ull
#define WS_NEEDED (RECS_BYTES + IMP_BYTES + CNT_BYTES + PTR_BYTES + CCOL_BYTES + CW_BYTES + 2ull * RND_BYTES + BSUM_BYTES)
// hist (50 MB u32) aliases recs_a (dead before recs_a first written). Buffer B
// (recs_b, 76.8 MB) aliases d_out: dense out written only by the last iteration.

// ---------- JAX threefry2x32 (20 rounds), exact replica ----------
__host__ __device__ __forceinline__ uint32_t rotl32(uint32_t x, int r) {
  return (x << r) | (x >> (32 - r));
}

__host__ __device__ __forceinline__ void threefry2x32(uint32_t k0, uint32_t k1,
                                                      uint32_t x0, uint32_t x1,
                                                      uint32_t& o0, uint32_t& o1) {
  uint32_t k2 = k0 ^ k1 ^ 0x1BD11BDAu;
  x0 += k0; x1 += k1;
  x0 += x1; x1 = rotl32(x1, 13) ^ x0;
  x0 += x1; x1 = rotl32(x1, 15) ^ x0;
  x0 += x1; x1 = rotl32(x1, 26) ^ x0;
  x0 += x1; x1 = rotl32(x1, 6)  ^ x0;
  x0 += k1; x1 += k2 + 1u;
  x0 += x1; x1 = rotl32(x1, 17) ^ x0;
  x0 += x1; x1 = rotl32(x1, 29) ^ x0;
  x0 += x1; x1 = rotl32(x1, 16) ^ x0;
  x0 += x1; x1 = rotl32(x1, 24) ^ x0;
  x0 += k2; x1 += k0 + 2u;
  x0 += x1; x1 = rotl32(x1, 13) ^ x0;
  x0 += x1; x1 = rotl32(x1, 15) ^ x0;
  x0 += x1; x1 = rotl32(x1, 26) ^ x0;
  x0 += x1; x1 = rotl32(x1, 6)  ^ x0;
  x0 += k0; x1 += k1 + 3u;
  x0 += x1; x1 = rotl32(x1, 17) ^ x0;
  x0 += x1; x1 = rotl32(x1, 29) ^ x0;
  x0 += x1; x1 = rotl32(x1, 16) ^ x0;
  x0 += x1; x1 = rotl32(x1, 24) ^ x0;
  x0 += k1; x1 += k2 + 4u;
  x0 += x1; x1 = rotl32(x1, 13) ^ x0;
  x0 += x1; x1 = rotl32(x1, 15) ^ x0;
  x0 += x1; x1 = rotl32(x1, 26) ^ x0;
  x0 += x1; x1 = rotl32(x1, 6)  ^ x0;
  x0 += k2; x1 += k0 + 5u;
  o0 = x0; o1 = x1;
}

__device__ __forceinline__ uint32_t jax_bits_part32(uint32_t k0, uint32_t k1, uint32_t j) {
  uint32_t o0, o1;
  threefry2x32(k0, k1, 0u, j, o0, o1);
  return o0 ^ o1;
}

// ---------- order-preserving CSR build ----------
// LDS per-chunk histogram: 2 half-row passes, 2 rows packed per u32 (counts
// < 3200 << 65536), native integer ds_add atomics, full u32 slice written out
// -> no global memset, no global atomics.
#define HALF_R 25000
__global__ __launch_bounds__(256) void chunk_hist(const int* __restrict__ rows,
                                                  int* __restrict__ hist) {
  __shared__ uint32_t lh[HALF_R / 2];   // 50 KB
  int c = blockIdx.x;
  int base = c * CHUNK_E;
  for (int pass = 0; pass < 2; ++pass) {
    int rlo = pass * HALF_R;
    for (int i = threadIdx.x; i < HALF_R / 2; i += 256) lh[i] = 0;
    __syncthreads();
    for (int i = threadIdx.x; i < CHUNK_E; i += 256) {
      int r = rows[base + i] - rlo;
      if ((unsigned)r < (unsigned)HALF_R)
        atomicAdd(&lh[r >> 1], 1u << ((r & 1) << 4));
    }
    __syncthreads();
    int* out = hist + (size_t)c * N_NODES + rlo;
    for (int i = threadIdx.x; i < HALF_R / 2; i += 256) {
      uint32_t v = lh[i];
      out[2 * i]     = (int)(v & 0xFFFFu);
      out[2 * i + 1] = (int)(v >> 16);
    }
    __syncthreads();
  }
}

// per-row exclusive scan across chunks; fused per-block sum (was scan_blk)
__global__ void row_scan(int* __restrict__ hist, int* __restrict__ cnt,
                         int* __restrict__ bsum) {
  int r = blockIdx.x * blockDim.x + threadIdx.x;
  int run = 0;
  if (r < N_NODES) {
    for (int c = 0; c < C_CHUNKS; ++c) {
      size_t idx = (size_t)c * N_NODES + r;
      int t = hist[idx];
      hist[idx] = run;
      run += t;
    }
    cnt[r] = run;
  }
  int s = run;
  #pragma unroll
  for (int off = 32; off > 0; off >>= 1) s += __shfl_xor(s, off, 64);
  __shared__ int wsum[4];
  if ((threadIdx.x & 63) == 0) wsum[threadIdx.x >> 6] = s;
  __syncthreads();
  if (threadIdx.x == 0) bsum[blockIdx.x] = wsum[0] + wsum[1] + wsum[2] + wsum[3];
}

#define SCAN_NB ((N_NODES + 255) / 256)   // 196
__global__ void scan_top(int* __restrict__ bsum) {   // 1 block, 256 threads
  int t = threadIdx.x;
  int lane = t & 63, wv = t >> 6;
  int v = (t < SCAN_NB) ? bsum[t] : 0;
  int incl = v;
  #pragma unroll
  for (int off = 1; off < 64; off <<= 1) {
    int u = __shfl_up(incl, off, 64);
    if (lane >= off) incl += u;
  }
  __shared__ int wtot[4];
  if (lane == 63) wtot[wv] = incl;
  __syncthreads();
  int woff = 0;
  for (int k = 0; k < 4; ++k) if (k < wv) woff += wtot[k];
  if (t < SCAN_NB) bsum[t] = woff + incl - v;   // exclusive base per block
}

__global__ void scan_apply(const int* __restrict__ cnt, const int* __restrict__ bbase,
                           int* __restrict__ ptr) {
  int b = blockIdx.x, t = threadIdx.x;
  int i = b * 256 + t;
  int lane = t & 63, wv = t >> 6;
  int v = (i < N_NODES) ? cnt[i] : 0;
  int incl = v;
  #pragma unroll
  for (int off = 1; off < 64; off <<= 1) {
    int u = __shfl_up(incl, off, 64);
    if (lane >= off) incl += u;
  }
  __shared__ int wtot[4];
  if (lane == 63) wtot[wv] = incl;
  __syncthreads();
  int woff = bbase[b];
  for (int k = 0; k < 4; ++k) if (k < wv) woff += wtot[k];
  int excl = woff + incl - v;
  if (i < N_NODES) ptr[i] = excl;
  if (i == N_NODES - 1) ptr[N_NODES] = excl + v;
}

// rank/count/lastlane of RV among this wave's 64 values
#define MATCH(RV, RANKV, CNTV, LASTV)                                     \
  { RANKV = 0; CNTV = 0; LASTV = 0;                                       \
    _Pragma("unroll 8")                                                   \
    for (int ii = 0; ii < 64; ++ii) {                                     \
      int ri_ = __shfl((RV), ii, 64);                                     \
      if (ri_ == (RV)) { CNTV++; if (ii < lane) RANKV++; LASTV = ii; }    \
    } }

// order-preserving scatter, 3-stage software pipeline per subchunk
__global__ __launch_bounds__(64) void scatter_par(
    const int* __restrict__ rows, const int* __restrict__ cols,
    const float* __restrict__ w, const int* __restrict__ ptr,
    int* __restrict__ hist, int* __restrict__ ccol, float* __restrict__ cw) {
  int c = blockIdx.x;
  int lane = threadIdx.x;
  int* h = hist + (size_t)c * N_NODES;
  int base = c * CHUNK_E;

  int rM = rows[base + lane], clM = cols[base + lane];
  float wvM = w[base + lane];
  int rankM, cntM, lastM;
  MATCH(rM, rankM, cntM, lastM)
  int rL = 0, clL = 0; float wvL = 0.f;
  if (NSUB > 1) {
    int e = base + 64 + lane;
    rL = rows[e]; clL = cols[e]; wvL = w[e];
  }
  for (int sub = 0; sub < NSUB; ++sub) {
    int oldM = 0;
    if (lane == lastM) oldM = atomicAdd(&h[rM], cntM);
    int rN = 0, clN = 0; float wvN = 0.f;
    if (sub + 2 < NSUB) {
      int e = base + (sub + 2) * 64 + lane;
      rN = rows[e]; clN = cols[e]; wvN = w[e];
    }
    int rankL = 0, cntL = 0, lastL = 0;
    if (sub + 1 < NSUB) { MATCH(rL, rankL, cntL, lastL) }
    int old = __shfl(oldM, lastM, 64);
    int pos = ptr[rM] + old + rankM;
    ccol[pos] = clM; cw[pos] = wvM;
    rM = rL; clM = clL; wvM = wvL; rankM = rankL; cntM = cntL; lastM = lastL;
    rL = rN; clL = clN; wvL = wvN;
  }
}

// ---------- pack: prefix scans -> rank-packed (val, gene-byteoff) + round padding ----------
__device__ __forceinline__ void pack_row(uint32_t* __restrict__ rec,
                                         unsigned char* __restrict__ rnd_out,
                                         int lane, const float* rv) {
  uint32_t vm = 0;
  #pragma unroll
  for (int j = 0; j < 8; ++j) vm |= (rv[j] != 0.f) ? (1u << j) : 0u;
  int pF = __popc(vm & 15u);
  int pS = __popc(vm >> 4);
  int iF = pF, iS = pS;
  #pragma unroll
  for (int off = 1; off < 64; off <<= 1) {
    int uF = __shfl_up(iF, off, 64);
    int uS = __shfl_up(iS, off, 64);
    if (lane >= off) { iF += uF; iS += uS; }
  }
  int rF = iF - pF, rS = iS - pS;          // exclusive prefixes
  int tF = __shfl(iF, 63, 64);             // total first-half nnz
  int tS = __shfl(iS, 63, 64);             // total second-half nnz
  int b0 = tF + rS;
  float* vr = (float*)rec;
  ushort* gr = (ushort*)(rec + 256);
  int o = rF;
  #pragma unroll
  for (int j = 0; j < 4; ++j)
    if (vm & (1u << j)) {
      if (o < 256) { vr[o] = rv[j]; gr[o] = (ushort)((4 * lane + j) << 2); }
      o++;
    }
  o = b0;
  #pragma unroll
  for (int j = 4; j < 8; ++j)
    if (vm & (1u << j)) {
      if (o < 256) { vr[o] = rv[j]; gr[o] = (ushort)((256 + 4 * lane + (j - 4)) << 2); }
      o++;
    }
  int nz = min(tF + tS, 256);
  int rounds = max(1, (nz + 63) >> 6);
  int mpad = rounds << 6;
  int p = nz + lane;                        // mpad - nz <= 63 -> one slot per lane
  if (p < mpad) { vr[p] = 0.f; gr[p] = (ushort)(2048 + ((p & 63) << 2)); }
  if (lane == 63) *rnd_out = (unsigned char)rounds;
}

// initial pack of dense x_in -> buffer A; also zeroes imp (replaces memset)
__global__ __launch_bounds__(256) void init_pack(const float* __restrict__ x,
                                                 uint32_t* __restrict__ recs,
                                                 unsigned char* __restrict__ rnd,
                                                 unsigned char* __restrict__ imp) {
  int wv = threadIdx.x >> 6, lane = threadIdx.x & 63;
  int r = blockIdx.x * 4 + wv;
  const float4* p4 = (const float4*)(x + (size_t)r * N_GENES);
  float4 pa = p4[lane], pb = p4[64 + lane];
  float rv[8] = {pa.x, pa.y, pa.z, pa.w, pb.x, pb.y, pb.z, pb.w};
  pack_row(recs + (size_t)r * REC_DW, rnd + r, lane, rv);
  imp[(size_t)r * 64 + lane] = 0;
}

// transposed LDS index for bucket b
__device__ __forceinline__ int tr(uint32_t b) {
  return (int)(((b & 3u) << 6) | (b >> 2));
}

__device__ __forceinline__ float readlane_f(float v, int i) {
  return __int_as_float(__builtin_amdgcn_readlane(__float_as_int(v), i));
}

// ---------- branchless padded gather, two-group depth-8 pipeline ----------
// Stage S: wave-uniform rounds rd / record base rc (SGPRs via readlane) +
// prefetched (val, byteoff) for rounds 0..1 (4 VGPR/stage). Rounds 2 (~7% of
// edges after it0) and 3 (~0.2%) loaded inline, hidden by co-resident waves.
// Dummy/stale consumes use wt=0: adds +/-0 at stale valid LDS addrs -> exact.
#define DECL_ST(S) int rd##S = 0; const uint32_t* rc##S = recs_p;         \
  float v0##S = 0.f, v1##S = 0.f;                                         \
  int g0##S = 0, g1##S = 0;

#define ISSUE(S, IDX)                                                     \
  if ((IDX) < n) {                                                        \
    int cc_ = __builtin_amdgcn_readlane(cld, (IDX));                      \
    rd##S = __builtin_amdgcn_readlane(rdv, (IDX));                        \
    rc##S = recs_p + (size_t)cc_ * REC_DW;                                \
    const float* vr_ = (const float*)rc##S;                               \
    const ushort* gr_ = (const ushort*)(rc##S + 256);                     \
    v0##S = vr_[lane]; g0##S = gr_[lane];                                 \
    if (rd##S > 1) { v1##S = vr_[64 + lane]; g1##S = gr_[64 + lane]; }    \
  }

// Plain RMW: LDS pipe in-order per wave -> per-gene add order is exactly the
// ascending edge order; mul/add rounded separately (contract off) == XLA
// segment_sum. Byte-offsets distinct within each round -> no same-address lanes.
#define CONSUME(S, IDX)                                                   \
  { float wt_ = readlane_f(wld, (IDX));                                   \
    { float* p_ = (float*)((char*)accL + g0##S);                          \
      *p_ = *p_ + wt_ * v0##S; }                                          \
    if (rd##S > 1) {                                                      \
      { float* p_ = (float*)((char*)accL + g1##S);                        \
        *p_ = *p_ + wt_ * v1##S; }                                        \
      if (rd##S > 2) {                                                    \
        float v2_ = ((const float*)rc##S)[128 + lane];                    \
        int g2_ = ((const ushort*)(rc##S + 256))[128 + lane];             \
        { float* p_ = (float*)((char*)accL + g2_);                        \
          *p_ = *p_ + wt_ * v2_; }                                        \
        if (rd##S > 3) {                                                  \
          float v3_ = ((const float*)rc##S)[192 + lane];                  \
          int g3_ = ((const ushort*)(rc##S + 256))[192 + lane];           \
          float* p_ = (float*)((char*)accL + g3_);                        \
          *p_ = *p_ + wt_ * v3_;                                          \
        }                                                                 \
      }                                                                   \
    } }

// ---------- fused propagate + select ----------
template <bool LAST>
__global__ __launch_bounds__(256) void prop_select(
    const uint32_t* __restrict__ recs_p, const unsigned char* __restrict__ rnd_p,
    const int* __restrict__ ptr, const int* __restrict__ ccol,
    const float* __restrict__ cw, unsigned char* __restrict__ imp,
    const int* __restrict__ cap_arr, uint32_t k0, uint32_t k1,
    uint32_t* __restrict__ recs_n, unsigned char* __restrict__ rnd_n,
    float* __restrict__ xdense) {
  #pragma clang fp contract(off)
  __shared__ int hist_s[4][256];
  __shared__ float accbuf[4][576];   // 512 genes + 64-slot padding scratch
  int wv = threadIdx.x >> 6;
  int lane = threadIdx.x & 63;
  int r = blockIdx.x * 4 + wv;
  int beg = ptr[r], end = ptr[r + 1];
  int* h = hist_s[wv];
  float* accL = accbuf[wv];

  unsigned char ibyte = imp[(size_t)r * 64 + lane];
  int cap = cap_arr[r];

  const float4 z4 = make_float4(0.f, 0.f, 0.f, 0.f);
  *(float4*)&accL[4 * lane] = z4;
  *(float4*)&accL[256 + 4 * lane] = z4;

  // ---- own-row scatter -> pv[8] (previous x values of row r, dense) ----
  float pv[8];
  {
    int rdR = rnd_p[r];
    const float* vrR = (const float*)(recs_p + (size_t)r * REC_DW);
    const ushort* grR = (const ushort*)(recs_p + (size_t)r * REC_DW + 256);
    for (int t = 0; t < (rdR << 6); t += 64) {
      float v = vrR[t + lane];
      int g = grR[t + lane];
      *(float*)((char*)accL + g) = v;   // padding assigns 0 to scratch
    }
    float4 a = *(float4*)&accL[4 * lane];
    float4 b = *(float4*)&accL[256 + 4 * lane];
    pv[0] = a.x; pv[1] = a.y; pv[2] = a.z; pv[3] = a.w;
    pv[4] = b.x; pv[5] = b.y; pv[6] = b.z; pv[7] = b.w;
    *(float4*)&accL[4 * lane] = z4;
    *(float4*)&accL[256 + 4 * lane] = z4;
  }

  // ---- gather-accumulate xp into accL (exact ascending edge order) ----
  for (int base2 = beg; base2 < end; base2 += 64) {
    int n = min(64, end - base2);
    int cld = ccol[base2 + min(lane, n - 1)];        // clamped: dummies = edge n-1
    float wld = (lane < n) ? cw[base2 + lane] : 0.f; // dummy weight 0 -> exact no-op
    int rdv = rnd_p[cld];

    DECL_ST(A) DECL_ST(B) DECL_ST(C) DECL_ST(D)
    DECL_ST(E) DECL_ST(F) DECL_ST(G) DECL_ST(H)
    ISSUE(A, 0) ISSUE(B, 1) ISSUE(C, 2) ISSUE(D, 3)
    int n8 = (n + 7) & ~7;
    for (int i = 0; i < n8; i += 8) {
      ISSUE(E, i + 4) ISSUE(F, i + 5) ISSUE(G, i + 6) ISSUE(H, i + 7)
      CONSUME(A, i)     CONSUME(B, i + 1) CONSUME(C, i + 2) CONSUME(D, i + 3)
      ISSUE(A, i + 8) ISSUE(B, i + 9) ISSUE(C, i + 10) ISSUE(D, i + 11)
      CONSUME(E, i + 4) CONSUME(F, i + 5) CONSUME(G, i + 6) CONSUME(H, i + 7)
    }
  }

  // ---- read accumulator back (in-order LDS pipe) ----
  float4 aa = *(float4*)&accL[4 * lane];
  float4 ab = *(float4*)&accL[256 + 4 * lane];
  float acc[8] = {aa.x, aa.y, aa.z, aa.w, ab.x, ab.y, ab.z, ab.w};

  // ---- merge: existing (orig nonzero) entries win ----
  float val[8];
  bool ex[8];
  #pragma unroll
  for (int j = 0; j < 8; ++j) {
    ex[j] = (pv[j] != 0.f) && !((ibyte >> j) & 1);
    val[j] = ex[j] ? pv[j] : acc[j];
  }

  // ---- valid mask & count ----
  bool valid[8];
  int cnt_local = 0;
  #pragma unroll
  for (int j = 0; j < 8; ++j) {
    bool im = ((ibyte >> j) & 1) || ((val[j] != 0.f) && !ex[j]);
    valid[j] = im;
    cnt_local += im ? 1 : 0;
  }
  int nimp = cnt_local;
  #pragma unroll
  for (int off = 32; off > 0; off >>= 1) nimp += __shfl_xor(nimp, off, 64);

  bool keep_all = (nimp <= cap);
  bool keep_none = (!keep_all) && (cap <= 0);
  uint32_t key[8];
  uint32_t T = 0;
  bool use_T = false;

  if (!keep_all && !keep_none) {   // wave-uniform branch
    uint32_t goff = (uint32_t)r * (uint32_t)N_GENES;
    #pragma unroll
    for (int j = 0; j < 8; ++j) {
      int g = (j < 4) ? (4 * lane + j) : (256 + 4 * lane + (j - 4));
      uint32_t b = jax_bits_part32(k0, k1, goff + (uint32_t)g);
      key[j] = ((b >> 9) << 9) | (uint32_t)g;
    }
    h[lane] = 0; h[lane + 64] = 0; h[lane + 128] = 0; h[lane + 192] = 0;
    #pragma unroll
    for (int j = 0; j < 8; ++j)
      if (valid[j]) atomicAdd(&h[tr(key[j] >> 24)], 1);
    __threadfence_block();
    int c0 = h[lane], c1 = h[64 + lane], c2 = h[128 + lane], c3 = h[192 + lane];
    int lsum = c0 + c1 + c2 + c3;
    int incl = lsum;
    #pragma unroll
    for (int off = 1; off < 64; off <<= 1) {
      int v = __shfl_up(incl, off, 64);
      if (lane >= off) incl += v;
    }
    int excl = incl - lsum;
    int foundB = -1, foundRem = 0, cum = excl;
    if (cap > cum && cap <= cum + c0) { foundB = 4 * lane;     foundRem = cap - cum; } cum += c0;
    if (foundB < 0 && cap > cum && cap <= cum + c1) { foundB = 4 * lane + 1; foundRem = cap - cum; } cum += c1;
    if (foundB < 0 && cap > cum && cap <= cum + c2) { foundB = 4 * lane + 2; foundRem = cap - cum; } cum += c2;
    if (foundB < 0 && cap > cum && cap <= cum + c3) { foundB = 4 * lane + 3; foundRem = cap - cum; }
    unsigned long long mbal = __ballot(foundB >= 0);
    int src = __ffsll(mbal) - 1;
    int B   = __shfl(foundB, src, 64);
    int rem = __shfl(foundRem, src, 64);
    unsigned cm = 0;
    #pragma unroll
    for (int j = 0; j < 8; ++j)
      if (valid[j] && (int)(key[j] >> 24) == B) cm |= (1u << j);
    for (;;) {
      uint32_t m = 0xFFFFFFFFu;
      #pragma unroll
      for (int j = 0; j < 8; ++j)
        if (cm & (1u << j)) m = min(m, key[j]);
      #pragma unroll
      for (int off = 32; off > 0; off >>= 1)
        m = min(m, (uint32_t)__shfl_xor((int)m, off, 64));
      if (rem == 1) { T = m; break; }
      #pragma unroll
      for (int j = 0; j < 8; ++j)
        if ((cm & (1u << j)) && key[j] == m) cm &= ~(1u << j);
      rem--;
    }
    use_T = true;
  }

  // ---- apply & write ----
  float rv[8]; unsigned char ob8 = 0;
  #pragma unroll
  for (int j = 0; j < 8; ++j) {
    bool keep = valid[j] && (keep_all || (use_T && key[j] <= T));
    ob8 |= (unsigned char)(keep ? (1u << j) : 0u);
    rv[j] = (valid[j] && !keep) ? 0.f : val[j];
  }
  if (LAST) {
    float4* x4 = (float4*)(xdense + (size_t)r * N_GENES);
    x4[lane]      = make_float4(rv[0], rv[1], rv[2], rv[3]);
    x4[64 + lane] = make_float4(rv[4], rv[5], rv[6], rv[7]);
  } else {
    pack_row(recs_n + (size_t)r * REC_DW, rnd_n + r, lane, rv);
    imp[(size_t)r * 64 + lane] = ob8;
  }
}

// diagnostic: only fires if workspace is smaller than we need
__global__ void ws_probe(float* out, unsigned long long ws_bytes, unsigned long long needed) {
  if (ws_bytes < needed) out[0] = (float)ws_bytes;
}

extern "C" void kernel_launch(void* const* d_in, const int* in_sizes, int n_in,
                              void* d_out, int out_size, void* d_ws, size_t ws_size,
                              hipStream_t stream) {
  const float* x_in = (const float*)d_in[0];
  const float* ew   = (const float*)d_in[1];
  const int*   ei   = (const int*)d_in[2];
  const int*   cap  = (const int*)d_in[3];
  const int* rows = ei;
  const int* cols = ei + N_EDGES;
  float* out = (float*)d_out;

  char* ws = (char*)d_ws;
  uint32_t* recs_a = (uint32_t*)ws;         ws += RECS_BYTES;
  unsigned char* imp = (unsigned char*)ws;  ws += IMP_BYTES;
  int* cnt = (int*)ws;                      ws += CNT_BYTES;
  int* ptr = (int*)ws;                      ws += PTR_BYTES;
  int* ccol = (int*)ws;                     ws += CCOL_BYTES;
  float* cw = (float*)ws;                   ws += CW_BYTES;
  unsigned char* rnd_a = (unsigned char*)ws; ws += RND_BYTES;
  unsigned char* rnd_b = (unsigned char*)ws; ws += RND_BYTES;
  int* bsum = (int*)ws;                     ws += BSUM_BYTES;
  int* hist = (int*)d_ws;   // aliases recs_a: dead before recs_a first written

  // buffer B aliases d_out (dense out written only by the last iteration)
  uint32_t* recs_b = (uint32_t*)d_out;

  chunk_hist<<<C_CHUNKS, 256, 0, stream>>>(rows, hist);
  row_scan<<<SCAN_NB, 256, 0, stream>>>(hist, cnt, bsum);
  scan_top<<<1, 256, 0, stream>>>(bsum);
  scan_apply<<<SCAN_NB, 256, 0, stream>>>(cnt, bsum, ptr);
  scatter_par<<<C_CHUNKS, 64, 0, stream>>>(rows, cols, ew, ptr, hist, ccol, cw);
  init_pack<<<N_NODES / 4, 256, 0, stream>>>(x_in, recs_a, rnd_a, imp);

  uint32_t key_it[N_ITERS][2];
  for (int it = 0; it < N_ITERS; ++it) {
    uint32_t o0, o1;
    threefry2x32(0u, 42u, 0u, (uint32_t)it, o0, o1);
    key_it[it][0] = o0; key_it[it][1] = o1;
  }

  for (int it = 0; it < N_ITERS - 1; ++it) {
    bool a2b = (it & 1) == 0;   // it0: A->B, it1: B->A, it2: A->B, it3: B->A
    prop_select<false><<<N_NODES / 4, 256, 0, stream>>>(
        a2b ? recs_a : recs_b, a2b ? rnd_a : rnd_b,
        ptr, ccol, cw, imp, cap, key_it[it][0], key_it[it][1],
        a2b ? recs_b : recs_a, a2b ? rnd_b : rnd_a, nullptr);
  }
  // it4 reads A, writes dense to out (clobbering B, which is dead)
  prop_select<true><<<N_NODES / 4, 256, 0, stream>>>(
      recs_a, rnd_a, ptr, ccol, cw, imp, cap,
      key_it[N_ITERS - 1][0], key_it[N_ITERS - 1][1],
      nullptr, nullptr, out);

  ws_probe<<<1, 1, 0, stream>>>(out, (unsigned long long)ws_size,
                                (unsigned long long)WS_NEEDED);
}

// Round 10
// 1060.495 us; speedup vs baseline: 1.1210x; 1.1210x over previous
//
#include <hip/hip_runtime.h>
#include <stdint.h>

#define N_NODES   50000
#define N_GENES   512
#define N_EDGES   800000
#define N_ITERS   5

#define C_CHUNKS  250
#define CHUNK_E   3200          // 250 * 3200 = 800000; 3200/64 = 50 subchunks exactly
#define NSUB      (CHUNK_E / 64)

// ---- packed-sparse x representation (one 1536-B record per row) ----
// rec dwords [0..255]   : packed nonzero VALUES (f32), padded with 0.0f to a
//                         multiple of 64 entries (1..4 "rounds").
// rec dwords [256..383] : gene LDS BYTE-OFFSETS (u16, gene<<2; padding entries
//                         point at the per-wave scratch area 2048 + 4*(pos&63),
//                         distinct per lane within a round).
// rounds (1..4) per row in a u8 array (rnd_a / rnd_b).
#define REC_DW     384
#define REC_BYTES  1536

// ws layout sizes (bytes)
#define RECS_BYTES (50000ull * REC_BYTES + 256ull)
#define IMP_BYTES  3200000ull
#define CNT_BYTES  200000ull
#define PTR_BYTES  200004ull
#define CCOL_BYTES 3200000ull
#define CW_BYTES   3200000ull
#define RND_BYTES  50048ull
#define BSUM_BYTES 1024ull
#define WS_NEEDED (RECS_BYTES + IMP_BYTES + CNT_BYTES + PTR_BYTES + CCOL_BYTES + CW_BYTES + 2ull * RND_BYTES + BSUM_BYTES)
// hist (50 MB u32) aliases recs_a (dead before recs_a first written). Buffer B
// (recs_b, 76.8 MB) aliases d_out: dense out written only by the last iteration.

// ---------- JAX threefry2x32 (20 rounds), exact replica ----------
__host__ __device__ __forceinline__ uint32_t rotl32(uint32_t x, int r) {
  return (x << r) | (x >> (32 - r));
}

__host__ __device__ __forceinline__ void threefry2x32(uint32_t k0, uint32_t k1,
                                                      uint32_t x0, uint32_t x1,
                                                      uint32_t& o0, uint32_t& o1) {
  uint32_t k2 = k0 ^ k1 ^ 0x1BD11BDAu;
  x0 += k0; x1 += k1;
  x0 += x1; x1 = rotl32(x1, 13) ^ x0;
  x0 += x1; x1 = rotl32(x1, 15) ^ x0;
  x0 += x1; x1 = rotl32(x1, 26) ^ x0;
  x0 += x1; x1 = rotl32(x1, 6)  ^ x0;
  x0 += k1; x1 += k2 + 1u;
  x0 += x1; x1 = rotl32(x1, 17) ^ x0;
  x0 += x1; x1 = rotl32(x1, 29) ^ x0;
  x0 += x1; x1 = rotl32(x1, 16) ^ x0;
  x0 += x1; x1 = rotl32(x1, 24) ^ x0;
  x0 += k2; x1 += k0 + 2u;
  x0 += x1; x1 = rotl32(x1, 13) ^ x0;
  x0 += x1; x1 = rotl32(x1, 15) ^ x0;
  x0 += x1; x1 = rotl32(x1, 26) ^ x0;
  x0 += x1; x1 = rotl32(x1, 6)  ^ x0;
  x0 += k0; x1 += k1 + 3u;
  x0 += x1; x1 = rotl32(x1, 17) ^ x0;
  x0 += x1; x1 = rotl32(x1, 29) ^ x0;
  x0 += x1; x1 = rotl32(x1, 16) ^ x0;
  x0 += x1; x1 = rotl32(x1, 24) ^ x0;
  x0 += k1; x1 += k2 + 4u;
  x0 += x1; x1 = rotl32(x1, 13) ^ x0;
  x0 += x1; x1 = rotl32(x1, 15) ^ x0;
  x0 += x1; x1 = rotl32(x1, 26) ^ x0;
  x0 += x1; x1 = rotl32(x1, 6)  ^ x0;
  x0 += k2; x1 += k0 + 5u;
  o0 = x0; o1 = x1;
}

__device__ __forceinline__ uint32_t jax_bits_part32(uint32_t k0, uint32_t k1, uint32_t j) {
  uint32_t o0, o1;
  threefry2x32(k0, k1, 0u, j, o0, o1);
  return o0 ^ o1;
}

// ---------- order-preserving CSR build ----------
// LDS per-chunk histogram: 2 half-row passes, 2 rows packed per u32 (counts
// < 3200 << 65536), native integer ds_add atomics, full u32 slice written out
// -> no global memset, no global atomics.
#define HALF_R 25000
__global__ __launch_bounds__(256) void chunk_hist(const int* __restrict__ rows,
                                                  int* __restrict__ hist) {
  __shared__ uint32_t lh[HALF_R / 2];   // 50 KB
  int c = blockIdx.x;
  int base = c * CHUNK_E;
  for (int pass = 0; pass < 2; ++pass) {
    int rlo = pass * HALF_R;
    for (int i = threadIdx.x; i < HALF_R / 2; i += 256) lh[i] = 0;
    __syncthreads();
    for (int i = threadIdx.x; i < CHUNK_E; i += 256) {
      int r = rows[base + i] - rlo;
      if ((unsigned)r < (unsigned)HALF_R)
        atomicAdd(&lh[r >> 1], 1u << ((r & 1) << 4));
    }
    __syncthreads();
    int* out = hist + (size_t)c * N_NODES + rlo;
    for (int i = threadIdx.x; i < HALF_R / 2; i += 256) {
      uint32_t v = lh[i];
      out[2 * i]     = (int)(v & 0xFFFFu);
      out[2 * i + 1] = (int)(v >> 16);
    }
    __syncthreads();
  }
}

// per-row exclusive scan across chunks; fused per-block sum (was scan_blk)
__global__ void row_scan(int* __restrict__ hist, int* __restrict__ cnt,
                         int* __restrict__ bsum) {
  int r = blockIdx.x * blockDim.x + threadIdx.x;
  int run = 0;
  if (r < N_NODES) {
    for (int c = 0; c < C_CHUNKS; ++c) {
      size_t idx = (size_t)c * N_NODES + r;
      int t = hist[idx];
      hist[idx] = run;
      run += t;
    }
    cnt[r] = run;
  }
  int s = run;
  #pragma unroll
  for (int off = 32; off > 0; off >>= 1) s += __shfl_xor(s, off, 64);
  __shared__ int wsum[4];
  if ((threadIdx.x & 63) == 0) wsum[threadIdx.x >> 6] = s;
  __syncthreads();
  if (threadIdx.x == 0) bsum[blockIdx.x] = wsum[0] + wsum[1] + wsum[2] + wsum[3];
}

#define SCAN_NB ((N_NODES + 255) / 256)   // 196
__global__ void scan_top(int* __restrict__ bsum) {   // 1 block, 256 threads
  int t = threadIdx.x;
  int lane = t & 63, wv = t >> 6;
  int v = (t < SCAN_NB) ? bsum[t] : 0;
  int incl = v;
  #pragma unroll
  for (int off = 1; off < 64; off <<= 1) {
    int u = __shfl_up(incl, off, 64);
    if (lane >= off) incl += u;
  }
  __shared__ int wtot[4];
  if (lane == 63) wtot[wv] = incl;
  __syncthreads();
  int woff = 0;
  for (int k = 0; k < 4; ++k) if (k < wv) woff += wtot[k];
  if (t < SCAN_NB) bsum[t] = woff + incl - v;   // exclusive base per block
}

__global__ void scan_apply(const int* __restrict__ cnt, const int* __restrict__ bbase,
                           int* __restrict__ ptr) {
  int b = blockIdx.x, t = threadIdx.x;
  int i = b * 256 + t;
  int lane = t & 63, wv = t >> 6;
  int v = (i < N_NODES) ? cnt[i] : 0;
  int incl = v;
  #pragma unroll
  for (int off = 1; off < 64; off <<= 1) {
    int u = __shfl_up(incl, off, 64);
    if (lane >= off) incl += u;
  }
  __shared__ int wtot[4];
  if (lane == 63) wtot[wv] = incl;
  __syncthreads();
  int woff = bbase[b];
  for (int k = 0; k < 4; ++k) if (k < wv) woff += wtot[k];
  int excl = woff + incl - v;
  if (i < N_NODES) ptr[i] = excl;
  if (i == N_NODES - 1) ptr[N_NODES] = excl + v;
}

// rank/count/lastlane of RV among this wave's 64 values
#define MATCH(RV, RANKV, CNTV, LASTV)                                     \
  { RANKV = 0; CNTV = 0; LASTV = 0;                                       \
    _Pragma("unroll 8")                                                   \
    for (int ii = 0; ii < 64; ++ii) {                                     \
      int ri_ = __shfl((RV), ii, 64);                                     \
      if (ri_ == (RV)) { CNTV++; if (ii < lane) RANKV++; LASTV = ii; }    \
    } }

// order-preserving scatter, 3-stage software pipeline per subchunk
__global__ __launch_bounds__(64) void scatter_par(
    const int* __restrict__ rows, const int* __restrict__ cols,
    const float* __restrict__ w, const int* __restrict__ ptr,
    int* __restrict__ hist, int* __restrict__ ccol, float* __restrict__ cw) {
  int c = blockIdx.x;
  int lane = threadIdx.x;
  int* h = hist + (size_t)c * N_NODES;
  int base = c * CHUNK_E;

  int rM = rows[base + lane], clM = cols[base + lane];
  float wvM = w[base + lane];
  int rankM, cntM, lastM;
  MATCH(rM, rankM, cntM, lastM)
  int rL = 0, clL = 0; float wvL = 0.f;
  if (NSUB > 1) {
    int e = base + 64 + lane;
    rL = rows[e]; clL = cols[e]; wvL = w[e];
  }
  for (int sub = 0; sub < NSUB; ++sub) {
    int oldM = 0;
    if (lane == lastM) oldM = atomicAdd(&h[rM], cntM);
    int rN = 0, clN = 0; float wvN = 0.f;
    if (sub + 2 < NSUB) {
      int e = base + (sub + 2) * 64 + lane;
      rN = rows[e]; clN = cols[e]; wvN = w[e];
    }
    int rankL = 0, cntL = 0, lastL = 0;
    if (sub + 1 < NSUB) { MATCH(rL, rankL, cntL, lastL) }
    int old = __shfl(oldM, lastM, 64);
    int pos = ptr[rM] + old + rankM;
    ccol[pos] = clM; cw[pos] = wvM;
    rM = rL; clM = clL; wvM = wvL; rankM = rankL; cntM = cntL; lastM = lastL;
    rL = rN; clL = clN; wvL = wvN;
  }
}

// ---------- pack: prefix scans -> rank-packed (val, gene-byteoff) + round padding ----------
__device__ __forceinline__ void pack_row(uint32_t* __restrict__ rec,
                                         unsigned char* __restrict__ rnd_out,
                                         int lane, const float* rv) {
  uint32_t vm = 0;
  #pragma unroll
  for (int j = 0; j < 8; ++j) vm |= (rv[j] != 0.f) ? (1u << j) : 0u;
  int pF = __popc(vm & 15u);
  int pS = __popc(vm >> 4);
  int iF = pF, iS = pS;
  #pragma unroll
  for (int off = 1; off < 64; off <<= 1) {
    int uF = __shfl_up(iF, off, 64);
    int uS = __shfl_up(iS, off, 64);
    if (lane >= off) { iF += uF; iS += uS; }
  }
  int rF = iF - pF, rS = iS - pS;          // exclusive prefixes
  int tF = __shfl(iF, 63, 64);             // total first-half nnz
  int tS = __shfl(iS, 63, 64);             // total second-half nnz
  int b0 = tF + rS;
  float* vr = (float*)rec;
  ushort* gr = (ushort*)(rec + 256);
  int o = rF;
  #pragma unroll
  for (int j = 0; j < 4; ++j)
    if (vm & (1u << j)) {
      if (o < 256) { vr[o] = rv[j]; gr[o] = (ushort)((4 * lane + j) << 2); }
      o++;
    }
  o = b0;
  #pragma unroll
  for (int j = 4; j < 8; ++j)
    if (vm & (1u << j)) {
      if (o < 256) { vr[o] = rv[j]; gr[o] = (ushort)((256 + 4 * lane + (j - 4)) << 2); }
      o++;
    }
  int nz = min(tF + tS, 256);
  int rounds = max(1, (nz + 63) >> 6);
  int mpad = rounds << 6;
  int p = nz + lane;                        // mpad - nz <= 63 -> one slot per lane
  if (p < mpad) { vr[p] = 0.f; gr[p] = (ushort)(2048 + ((p & 63) << 2)); }
  if (lane == 63) *rnd_out = (unsigned char)rounds;
}

// initial pack of dense x_in -> buffer A; also zeroes imp (replaces memset)
__global__ __launch_bounds__(256) void init_pack(const float* __restrict__ x,
                                                 uint32_t* __restrict__ recs,
                                                 unsigned char* __restrict__ rnd,
                                                 unsigned char* __restrict__ imp) {
  int wv = threadIdx.x >> 6, lane = threadIdx.x & 63;
  int r = blockIdx.x * 4 + wv;
  const float4* p4 = (const float4*)(x + (size_t)r * N_GENES);
  float4 pa = p4[lane], pb = p4[64 + lane];
  float rv[8] = {pa.x, pa.y, pa.z, pa.w, pb.x, pb.y, pb.z, pb.w};
  pack_row(recs + (size_t)r * REC_DW, rnd + r, lane, rv);
  imp[(size_t)r * 64 + lane] = 0;
}

// transposed LDS index for bucket b
__device__ __forceinline__ int tr(uint32_t b) {
  return (int)(((b & 3u) << 6) | (b >> 2));
}

__device__ __forceinline__ float readlane_f(float v, int i) {
  return __int_as_float(__builtin_amdgcn_readlane(__float_as_int(v), i));
}

// ---------- branchless padded gather, depth-4 pipeline (R8 config: proven) ----------
// Stage S: wave-uniform rounds rd (SGPR) + prefetched (val, byteoff) for rounds
// 0..2. Round 3 (~0.2% of edges) loaded inline. Dummy/stale consumes use wt=0:
// adds +/-0 at a stale (valid) LDS address -> bits unchanged, exact.
#define DECL_ST(S) int rd##S = 0; const uint32_t* rc##S = recs_p;         \
  float v0##S = 0.f, v1##S = 0.f, v2##S = 0.f;                            \
  int g0##S = 0, g1##S = 0, g2##S = 0;

#define ISSUE(S, IDX)                                                     \
  if ((IDX) < n) {                                                        \
    int cc_ = __builtin_amdgcn_readlane(cld, (IDX));                      \
    rd##S = __builtin_amdgcn_readlane(rdv, (IDX));                        \
    rc##S = recs_p + (size_t)cc_ * REC_DW;                                \
    const float* vr_ = (const float*)rc##S;                               \
    const ushort* gr_ = (const ushort*)(rc##S + 256);                     \
    v0##S = vr_[lane]; g0##S = gr_[lane];                                 \
    if (rd##S > 1) {                                                      \
      v1##S = vr_[64 + lane]; g1##S = gr_[64 + lane];                     \
      if (rd##S > 2) { v2##S = vr_[128 + lane]; g2##S = gr_[128 + lane]; }\
    }                                                                     \
  }

// Plain RMW: LDS pipe is in-order per wave -> per-gene add order is exactly the
// ascending edge order; mul/add rounded separately (contract off) == XLA
// segment_sum. Byte-offsets distinct within each round (real genes distinct,
// padding per-lane distinct) -> no same-address lanes within one RMW.
#define CONSUME(S, IDX)                                                   \
  { float wt_ = readlane_f(wld, (IDX));                                   \
    { float* p_ = (float*)((char*)accL + g0##S);                          \
      *p_ = *p_ + wt_ * v0##S; }                                          \
    if (rd##S > 1) {                                                      \
      { float* p_ = (float*)((char*)accL + g1##S);                        \
        *p_ = *p_ + wt_ * v1##S; }                                        \
      if (rd##S > 2) {                                                    \
        { float* p_ = (float*)((char*)accL + g2##S);                      \
          *p_ = *p_ + wt_ * v2##S; }                                      \
        if (rd##S > 3) {                                                  \
          float v3_ = ((const float*)rc##S)[192 + lane];                  \
          int g3_ = ((const ushort*)(rc##S + 256))[192 + lane];           \
          float* p_ = (float*)((char*)accL + g3_);                        \
          *p_ = *p_ + wt_ * v3_;                                          \
        }                                                                 \
      }                                                                   \
    } }

// ---------- fused propagate + select ----------
template <bool LAST>
__global__ __launch_bounds__(256) void prop_select(
    const uint32_t* __restrict__ recs_p, const unsigned char* __restrict__ rnd_p,
    const int* __restrict__ ptr, const int* __restrict__ ccol,
    const float* __restrict__ cw, unsigned char* __restrict__ imp,
    const int* __restrict__ cap_arr, uint32_t k0, uint32_t k1,
    uint32_t* __restrict__ recs_n, unsigned char* __restrict__ rnd_n,
    float* __restrict__ xdense) {
  #pragma clang fp contract(off)
  __shared__ int hist_s[4][256];
  __shared__ float accbuf[4][576];   // 512 genes + 64-slot padding scratch
  int wv = threadIdx.x >> 6;
  int lane = threadIdx.x & 63;
  int r = blockIdx.x * 4 + wv;
  int beg = ptr[r], end = ptr[r + 1];
  int* h = hist_s[wv];
  float* accL = accbuf[wv];

  unsigned char ibyte = imp[(size_t)r * 64 + lane];
  int cap = cap_arr[r];

  const float4 z4 = make_float4(0.f, 0.f, 0.f, 0.f);
  *(float4*)&accL[4 * lane] = z4;
  *(float4*)&accL[256 + 4 * lane] = z4;

  // ---- own-row scatter -> pv[8] (previous x values of row r, dense) ----
  float pv[8];
  {
    int rdR = rnd_p[r];
    const float* vrR = (const float*)(recs_p + (size_t)r * REC_DW);
    const ushort* grR = (const ushort*)(recs_p + (size_t)r * REC_DW + 256);
    for (int t = 0; t < (rdR << 6); t += 64) {
      float v = vrR[t + lane];
      int g = grR[t + lane];
      *(float*)((char*)accL + g) = v;   // padding assigns 0 to scratch
    }
    float4 a = *(float4*)&accL[4 * lane];
    float4 b = *(float4*)&accL[256 + 4 * lane];
    pv[0] = a.x; pv[1] = a.y; pv[2] = a.z; pv[3] = a.w;
    pv[4] = b.x; pv[5] = b.y; pv[6] = b.z; pv[7] = b.w;
    *(float4*)&accL[4 * lane] = z4;
    *(float4*)&accL[256 + 4 * lane] = z4;
  }

  // ---- gather-accumulate xp into accL (exact ascending edge order) ----
  for (int base2 = beg; base2 < end; base2 += 64) {
    int n = min(64, end - base2);
    int cld = ccol[base2 + min(lane, n - 1)];        // clamped: dummies = edge n-1
    float wld = (lane < n) ? cw[base2 + lane] : 0.f; // dummy weight 0 -> exact no-op
    int rdv = rnd_p[cld];

    DECL_ST(A) DECL_ST(B) DECL_ST(C) DECL_ST(D)
    ISSUE(A, 0) ISSUE(B, 1) ISSUE(C, 2) ISSUE(D, 3)
    int n4 = (n + 3) & ~3;
    for (int i = 0; i < n4; i += 4) {
      CONSUME(A, i)     ISSUE(A, i + 4)
      CONSUME(B, i + 1) ISSUE(B, i + 5)
      CONSUME(C, i + 2) ISSUE(C, i + 6)
      CONSUME(D, i + 3) ISSUE(D, i + 7)
    }
  }

  // ---- read accumulator back (in-order LDS pipe) ----
  float4 aa = *(float4*)&accL[4 * lane];
  float4 ab = *(float4*)&accL[256 + 4 * lane];
  float acc[8] = {aa.x, aa.y, aa.z, aa.w, ab.x, ab.y, ab.z, ab.w};

  // ---- merge: existing (orig nonzero) entries win ----
  float val[8];
  bool ex[8];
  #pragma unroll
  for (int j = 0; j < 8; ++j) {
    ex[j] = (pv[j] != 0.f) && !((ibyte >> j) & 1);
    val[j] = ex[j] ? pv[j] : acc[j];
  }

  // ---- valid mask & count ----
  bool valid[8];
  int cnt_local = 0;
  #pragma unroll
  for (int j = 0; j < 8; ++j) {
    bool im = ((ibyte >> j) & 1) || ((val[j] != 0.f) && !ex[j]);
    valid[j] = im;
    cnt_local += im ? 1 : 0;
  }
  int nimp = cnt_local;
  #pragma unroll
  for (int off = 32; off > 0; off >>= 1) nimp += __shfl_xor(nimp, off, 64);

  bool keep_all = (nimp <= cap);
  bool keep_none = (!keep_all) && (cap <= 0);
  uint32_t key[8];
  uint32_t T = 0;
  bool use_T = false;

  if (!keep_all && !keep_none) {   // wave-uniform branch
    uint32_t goff = (uint32_t)r * (uint32_t)N_GENES;
    #pragma unroll
    for (int j = 0; j < 8; ++j) {
      int g = (j < 4) ? (4 * lane + j) : (256 + 4 * lane + (j - 4));
      uint32_t b = jax_bits_part32(k0, k1, goff + (uint32_t)g);
      key[j] = ((b >> 9) << 9) | (uint32_t)g;
    }
    h[lane] = 0; h[lane + 64] = 0; h[lane + 128] = 0; h[lane + 192] = 0;
    #pragma unroll
    for (int j = 0; j < 8; ++j)
      if (valid[j]) atomicAdd(&h[tr(key[j] >> 24)], 1);
    __threadfence_block();
    int c0 = h[lane], c1 = h[64 + lane], c2 = h[128 + lane], c3 = h[192 + lane];
    int lsum = c0 + c1 + c2 + c3;
    int incl = lsum;
    #pragma unroll
    for (int off = 1; off < 64; off <<= 1) {
      int v = __shfl_up(incl, off, 64);
      if (lane >= off) incl += v;
    }
    int excl = incl - lsum;
    int foundB = -1, foundRem = 0, cum = excl;
    if (cap > cum && cap <= cum + c0) { foundB = 4 * lane;     foundRem = cap - cum; } cum += c0;
    if (foundB < 0 && cap > cum && cap <= cum + c1) { foundB = 4 * lane + 1; foundRem = cap - cum; } cum += c1;
    if (foundB < 0 && cap > cum && cap <= cum + c2) { foundB = 4 * lane + 2; foundRem = cap - cum; } cum += c2;
    if (foundB < 0 && cap > cum && cap <= cum + c3) { foundB = 4 * lane + 3; foundRem = cap - cum; }
    unsigned long long mbal = __ballot(foundB >= 0);
    int src = __ffsll(mbal) - 1;
    int B   = __shfl(foundB, src, 64);
    int rem = __shfl(foundRem, src, 64);
    unsigned cm = 0;
    #pragma unroll
    for (int j = 0; j < 8; ++j)
      if (valid[j] && (int)(key[j] >> 24) == B) cm |= (1u << j);
    for (;;) {
      uint32_t m = 0xFFFFFFFFu;
      #pragma unroll
      for (int j = 0; j < 8; ++j)
        if (cm & (1u << j)) m = min(m, key[j]);
      #pragma unroll
      for (int off = 32; off > 0; off >>= 1)
        m = min(m, (uint32_t)__shfl_xor((int)m, off, 64));
      if (rem == 1) { T = m; break; }
      #pragma unroll
      for (int j = 0; j < 8; ++j)
        if ((cm & (1u << j)) && key[j] == m) cm &= ~(1u << j);
      rem--;
    }
    use_T = true;
  }

  // ---- apply & write ----
  float rv[8]; unsigned char ob8 = 0;
  #pragma unroll
  for (int j = 0; j < 8; ++j) {
    bool keep = valid[j] && (keep_all || (use_T && key[j] <= T));
    ob8 |= (unsigned char)(keep ? (1u << j) : 0u);
    rv[j] = (valid[j] && !keep) ? 0.f : val[j];
  }
  if (LAST) {
    float4* x4 = (float4*)(xdense + (size_t)r * N_GENES);
    x4[lane]      = make_float4(rv[0], rv[1], rv[2], rv[3]);
    x4[64 + lane] = make_float4(rv[4], rv[5], rv[6], rv[7]);
  } else {
    pack_row(recs_n + (size_t)r * REC_DW, rnd_n + r, lane, rv);
    imp[(size_t)r * 64 + lane] = ob8;
  }
}

// diagnostic: only fires if workspace is smaller than we need
__global__ void ws_probe(float* out, unsigned long long ws_bytes, unsigned long long needed) {
  if (ws_bytes < needed) out[0] = (float)ws_bytes;
}

extern "C" void kernel_launch(void* const* d_in, const int* in_sizes, int n_in,
                              void* d_out, int out_size, void* d_ws, size_t ws_size,
                              hipStream_t stream) {
  const float* x_in = (const float*)d_in[0];
  const float* ew   = (const float*)d_in[1];
  const int*   ei   = (const int*)d_in[2];
  const int*   cap  = (const int*)d_in[3];
  const int* rows = ei;
  const int* cols = ei + N_EDGES;
  float* out = (float*)d_out;

  char* ws = (char*)d_ws;
  uint32_t* recs_a = (uint32_t*)ws;         ws += RECS_BYTES;
  unsigned char* imp = (unsigned char*)ws;  ws += IMP_BYTES;
  int* cnt = (int*)ws;                      ws += CNT_BYTES;
  int* ptr = (int*)ws;                      ws += PTR_BYTES;
  int* ccol = (int*)ws;                     ws += CCOL_BYTES;
  float* cw = (float*)ws;                   ws += CW_BYTES;
  unsigned char* rnd_a = (unsigned char*)ws; ws += RND_BYTES;
  unsigned char* rnd_b = (unsigned char*)ws; ws += RND_BYTES;
  int* bsum = (int*)ws;                     ws += BSUM_BYTES;
  int* hist = (int*)d_ws;   // aliases recs_a: dead before recs_a first written

  // buffer B aliases d_out (dense out written only by the last iteration)
  uint32_t* recs_b = (uint32_t*)d_out;

  chunk_hist<<<C_CHUNKS, 256, 0, stream>>>(rows, hist);
  row_scan<<<SCAN_NB, 256, 0, stream>>>(hist, cnt, bsum);
  scan_top<<<1, 256, 0, stream>>>(bsum);
  scan_apply<<<SCAN_NB, 256, 0, stream>>>(cnt, bsum, ptr);
  scatter_par<<<C_CHUNKS, 64, 0, stream>>>(rows, cols, ew, ptr, hist, ccol, cw);
  init_pack<<<N_NODES / 4, 256, 0, stream>>>(x_in, recs_a, rnd_a, imp);

  uint32_t key_it[N_ITERS][2];
  for (int it = 0; it < N_ITERS; ++it) {
    uint32_t o0, o1;
    threefry2x32(0u, 42u, 0u, (uint32_t)it, o0, o1);
    key_it[it][0] = o0; key_it[it][1] = o1;
  }

  for (int it = 0; it < N_ITERS - 1; ++it) {
    bool a2b = (it & 1) == 0;   // it0: A->B, it1: B->A, it2: A->B, it3: B->A
    prop_select<false><<<N_NODES / 4, 256, 0, stream>>>(
        a2b ? recs_a : recs_b, a2b ? rnd_a : rnd_b,
        ptr, ccol, cw, imp, cap, key_it[it][0], key_it[it][1],
        a2b ? recs_b : recs_a, a2b ? rnd_b : rnd_a, nullptr);
  }
  // it4 reads A, writes dense to out (clobbering B, which is dead)
  prop_select<true><<<N_NODES / 4, 256, 0, stream>>>(
      recs_a, rnd_a, ptr, ccol, cw, imp, cap,
      key_it[N_ITERS - 1][0], key_it[N_ITERS - 1][1],
      nullptr, nullptr, out);

  ws_probe<<<1, 1, 0, stream>>>(out, (unsigned long long)ws_size,
                                (unsigned long long)WS_NEEDED);
}